// Round 12
// baseline (302.700 us; speedup 1.0000x reference)
//
#include <hip/hip_runtime.h>
#include <cstdint>
#include <cstddef>

#define BB 2
#define QQ 2048
#define KK_ 2048
#define HH 16
#define DD 64
#define DVV 64

static constexpr size_t CTX_ELEMS = (size_t)BB * QQ * HH * DVV;  // 4,194,304
#define LOG2E 1.44269504088896f
#define QSCALE (LOG2E / 8.0f)

typedef _Float16 f16x8 __attribute__((ext_vector_type(8)));
typedef _Float16 f16x4 __attribute__((ext_vector_type(4)));
typedef _Float16 f16x2 __attribute__((ext_vector_type(2)));
typedef float    f32x4 __attribute__((ext_vector_type(4)));

__device__ __forceinline__ float fexp2(float x) {
  float r;
  asm("v_exp_f32 %0, %1" : "=v"(r) : "v"(x));
  return r;
}

// workspace layout (float offsets)
#define RQ_OFF    0        // [B][H][Q]  0.125*||q_row||
#define KPART_OFF 65536    // [B*H][8]   partial max ||k_row|| per chunk
#define M_OFF     65792    // [B][H][Q]  upper bound M per row

// ---------------------------------------------------------------------------
// Prep A: per (b,h,chunk): rq rows + partial kmax (over valid k only).
// ---------------------------------------------------------------------------
__global__ __launch_bounds__(256)
void prep_norms(const float* __restrict__ qs, const float* __restrict__ ks,
                const int* __restrict__ vlen, float* __restrict__ ws) {
  float* rq    = ws + RQ_OFF;
  float* kpart = ws + KPART_OFF;
  const int id = blockIdx.x;            // 0..255
  const int bh = id & 31, c = id >> 5;  // chunk 0..7
  const int h = bh & 15, b = bh >> 4;
  const int vl = vlen[b];
  const int t = threadIdx.x;
  const int grp = t >> 4, l16 = t & 15;
  const int w = t >> 6, l = t & 63;
  __shared__ float red[4];
  float km2 = 0.f;                      // max squared norm
  const int base = c * 256;
  for (int i = 0; i < 16; ++i) {
    const int r = base + i * 16 + grp;
    {
      const float4 v = *(const float4*)(qs + ((size_t)(b * QQ + r) * HH + h) * DD + l16 * 4);
      float s = v.x * v.x + v.y * v.y + v.z * v.z + v.w * v.w;
      s += __shfl_xor(s, 1); s += __shfl_xor(s, 2);
      s += __shfl_xor(s, 4); s += __shfl_xor(s, 8);
      if (l16 == 0) rq[(size_t)(b * HH + h) * QQ + r] = sqrtf(s) * 0.125f;
    }
    if (r < vl) {
      const float4 v = *(const float4*)(ks + ((size_t)(b * KK_ + r) * HH + h) * DD + l16 * 4);
      float s = v.x * v.x + v.y * v.y + v.z * v.z + v.w * v.w;
      s += __shfl_xor(s, 1); s += __shfl_xor(s, 2);
      s += __shfl_xor(s, 4); s += __shfl_xor(s, 8);
      km2 = fmaxf(km2, s);
    }
  }
  km2 = fmaxf(km2, __shfl_xor(km2, 16));
  km2 = fmaxf(km2, __shfl_xor(km2, 32));
  if (l == 0) red[w] = km2;
  __syncthreads();
  if (t == 0)
    kpart[bh * 8 + c] = sqrtf(fmaxf(fmaxf(red[0], red[1]), fmaxf(red[2], red[3])));
}

// ---------------------------------------------------------------------------
// Prep B: per (b,q): Brow = max_{k<vl} bias[q,k]; M[b,h,q] = rq*kmax + Brow.
// ---------------------------------------------------------------------------
__global__ __launch_bounds__(256)
void prep_m(const float* __restrict__ bias, const int* __restrict__ vlen,
            float* __restrict__ ws) {
  const float* rq    = ws + RQ_OFF;
  const float* kpart = ws + KPART_OFF;
  float* M = ws + M_OFF;
  const int id = blockIdx.x;            // 0..1023
  const int b = id >> 9;
  const int qb = (id & 511) * 4;
  const int t = threadIdx.x, w = t >> 6, l = t & 63;
  const int q = qb + w;
  const int vl = vlen[b];
  float m = -3e38f;
  for (int k0 = l * 4; k0 < vl; k0 += 256) {
    const float4 v = *(const float4*)(bias + (size_t)q * KK_ + k0);
    m = fmaxf(m, (k0 + 0 < vl) ? v.x : -3e38f);
    m = fmaxf(m, (k0 + 1 < vl) ? v.y : -3e38f);
    m = fmaxf(m, (k0 + 2 < vl) ? v.z : -3e38f);
    m = fmaxf(m, (k0 + 3 < vl) ? v.w : -3e38f);
  }
#pragma unroll
  for (int off = 1; off < 64; off <<= 1) m = fmaxf(m, __shfl_xor(m, off));
  if (l < 16) {
    const int h = l;
    float kmx = 0.f;
#pragma unroll
    for (int cc = 0; cc < 8; ++cc) kmx = fmaxf(kmx, kpart[(b * HH + h) * 8 + cc]);
    M[(size_t)(b * HH + h) * QQ + q] = rq[(size_t)(b * HH + h) * QQ + q] * kmx + m;
  }
}

// ---------------------------------------------------------------------------
// Main fused kernel. wg = (b,h, 128 q-rows), 1024 thr (16 waves).
// Wave pair (rg, kh): both own q-rows [rg*16, rg*16+16); kh=0 computes
// c-blocks {0,1} of each 64-k tile, kh=1 computes {2,3}. Half work per wave,
// 2x waves -> grid 512 x 1024thr = 2 blocks/CU = 32 waves/CU (max TLP).
// kh=0 waves stage K, kh=1 stage V. lsum pair-combined via small LDS buf;
// accv pair-reduced at the end via LDS overlay of the dead K/V buffers.
// Everything else as proven: fixed-M + exp2 folding, dbuf + 1 barrier/tile,
// P^T-in-register PV (mfma 16x16x16), XCD swizzle, last-tile-only masking.
// ---------------------------------------------------------------------------
__global__ __launch_bounds__(1024, 8)
void fused_attn(const float* __restrict__ qs, const float* __restrict__ ks,
                const float* __restrict__ vs, const float* __restrict__ bias,
                const int* __restrict__ vlen, const float* __restrict__ ws,
                float* __restrict__ dout) {
  float* ctx  = dout;
  float* attn = dout + CTX_ELEMS;
  const float* Mbuf = ws + M_OFF;

  // XCD swizzle: XCD x owns q-tiles {2x,2x+1} x all 32 bh (bias 2MB/XCD in L2)
  const int x   = blockIdx.x;           // 0..511
  const int xcd = x & 7;
  const int j   = x >> 3;               // 0..63
  const int qt  = xcd * 2 + (j & 1);    // 0..15 (128-row tiles)
  const int bh  = j >> 1;               // 0..31
  const int h   = bh & 15, b = bh >> 4;
  const int vl  = vlen[b];
  const int ntv = (vl + 63) >> 6;       // valid 64-tiles (>=1)

  const int t = threadIdx.x;
  const int w = t >> 6, l = t & 63, fr = l & 15, g = l >> 4;
  const int rg = w & 7;                 // row-group 0..7
  const int kh = w >> 3;                // k-half 0/1
  const int q0 = qt * 128, qw = q0 + rg * 16;
  const int myq = qw + fr;

  // LDS carve: Kl dbuf 18432 B + Vt dbuf 18432 B = 36864 B.
  // lsb (1 KB) overlays Vt space (idle in pass 1 epilogue);
  // red (36864 B, [8][64][18] f32) overlays everything (after final barrier).
  __shared__ __align__(16) unsigned char smem[36864];
  _Float16 (*Kl)[64][72] = reinterpret_cast<_Float16(*)[64][72]>(smem);
  _Float16 (*Vt)[64][72] = reinterpret_cast<_Float16(*)[64][72]>(smem + 18432);
  float* lsb = reinterpret_cast<float*>(smem + 18432);  // [2][8][16]
  float* red = reinterpret_cast<float*>(smem);          // [8][64][18]

  // ---- zero-fill fully-masked attn tail (posted early; drains in pass 1) ----
  {
    const int row = t >> 3;             // 0..127
    const int c0  = (t & 7) << 3;       // 8-float chunk
    float* ap = attn + ((size_t)(b * HH + h) * QQ + q0 + row) * KK_ + c0;
    const f32x4 z = {0.f, 0.f, 0.f, 0.f};
    for (int k0 = ntv * 64; k0 < KK_; k0 += 64) {
      *(f32x4*)(ap + k0)     = z;
      *(f32x4*)(ap + k0 + 4) = z;
    }
  }

  // ---- Q B-fragment in registers, pre-scaled by log2e/8 ----
  f16x8 bq[2];
  {
    const float* qp = qs + ((size_t)(b * QQ + myq) * HH + h) * DD + g * 8;
#pragma unroll
    for (int kk = 0; kk < 2; ++kk) {
      const float4 f0 = *(const float4*)(qp + kk * 32);
      const float4 f1 = *(const float4*)(qp + kk * 32 + 4);
      f16x8 v;
      v[0] = (_Float16)(f0.x * QSCALE); v[1] = (_Float16)(f0.y * QSCALE);
      v[2] = (_Float16)(f0.z * QSCALE); v[3] = (_Float16)(f0.w * QSCALE);
      v[4] = (_Float16)(f1.x * QSCALE); v[5] = (_Float16)(f1.y * QSCALE);
      v[6] = (_Float16)(f1.z * QSCALE); v[7] = (_Float16)(f1.w * QSCALE);
      bq[kk] = v;
    }
  }

  const float Mq2 = Mbuf[(size_t)(b * HH + h) * QQ + myq] * LOG2E;
  const float* biasq = bias + (size_t)myq * KK_;
  float* attnq = attn + ((size_t)(b * HH + h) * QQ + myq) * KK_;

  // staging split: kh==0 waves (t<512) stage K; kh==1 stage V
  const bool sk = (kh == 0);
  const int ts = t & 511;
  const int krow = ts >> 3, kc0 = (ts & 7) << 3;   // K: 2 float4 per thread
  const int rho = ts & 31, dlt = ts >> 5;          // V: pair rows, 4 dv cols

#define KADDR(k) (ks + ((size_t)(b * KK_ + (k)) * HH + h) * DD)
#define VADDR(k) (vs + ((size_t)(b * KK_ + (k)) * HH + h) * DVV)

#define LOAD_K(k0arg)                                      \
  do {                                                     \
    const float* kp = KADDR((k0arg) + krow) + kc0;         \
    kr[0] = ((const float4*)kp)[0];                        \
    kr[1] = ((const float4*)kp)[1];                        \
  } while (0)

#define STORE_K(buf)                                       \
  do {                                                     \
    _Pragma("unroll") for (int i = 0; i < 2; ++i) {        \
      f16x4 hv;                                            \
      hv[0] = (_Float16)kr[i].x; hv[1] = (_Float16)kr[i].y;\
      hv[2] = (_Float16)kr[i].z; hv[3] = (_Float16)kr[i].w;\
      *(f16x4*)&Kl[buf][krow][kc0 + i * 4] = hv;           \
    }                                                      \
  } while (0)

#define LOAD_V(k0arg)                                      \
  do {                                                     \
    kr[0] = *(const float4*)(VADDR((k0arg) + 2 * rho) + dlt * 4);     \
    kr[1] = *(const float4*)(VADDR((k0arg) + 2 * rho + 1) + dlt * 4); \
  } while (0)

#define STORE_V(buf)                                       \
  do {                                                     \
    const float a0[4] = {kr[0].x, kr[0].y, kr[0].z, kr[0].w}; \
    const float a1[4] = {kr[1].x, kr[1].y, kr[1].z, kr[1].w}; \
    _Pragma("unroll") for (int i = 0; i < 4; ++i) {        \
      f16x2 pk; pk[0] = (_Float16)a0[i]; pk[1] = (_Float16)a1[i];\
      *(f16x2*)&Vt[buf][dlt * 4 + i][2 * rho] = pk;        \
    }                                                      \
  } while (0)

  float4 kr[2];
  int cur = 0;

  // ================= PASS 1: lsum (1 barrier/tile) ==========================
  if (sk) { LOAD_K(0); STORE_K(0); }
  __syncthreads();

  float lsum = 0.f;
  for (int it = 0; it < ntv; ++it) {
    const int k0 = it * 64;
    const bool pre = (it + 1 < ntv);
    const bool lastt = (it == ntv - 1);
    if (pre && sk) LOAD_K(k0 + 64);
#pragma unroll
    for (int cc = 0; cc < 2; ++cc) {
      const int c = kh * 2 + cc;
      const int kb = k0 + c * 16 + g * 4;
      const float4 bz = *(const float4*)(biasq + kb);
      const f16x8 ka0 = *(const f16x8*)&Kl[cur][c * 16 + fr][g * 8];
      const f16x8 ka1 = *(const f16x8*)&Kl[cur][c * 16 + fr][32 + g * 8];
      f32x4 acc = {-Mq2, -Mq2, -Mq2, -Mq2};
      acc = __builtin_amdgcn_mfma_f32_16x16x32_f16(ka0, bq[0], acc, 0, 0, 0);
      acc = __builtin_amdgcn_mfma_f32_16x16x32_f16(ka1, bq[1], acc, 0, 0, 0);
      float e[4];
#pragma unroll
      for (int r = 0; r < 4; ++r) e[r] = fexp2(fmaf(bz[r], LOG2E, acc[r]));
      if (lastt) {
#pragma unroll
        for (int r = 0; r < 4; ++r) e[r] = (kb + r < vl) ? e[r] : 0.f;
      }
      lsum += (e[0] + e[1]) + (e[2] + e[3]);
    }
    if (pre && sk) STORE_K(cur ^ 1);
    __syncthreads();             // ONE barrier per tile
    cur ^= 1;
  }
  lsum += __shfl_xor(lsum, 16);
  lsum += __shfl_xor(lsum, 32);
  // combine the two k-halves of the pair
  if (l < 16) lsb[(kh * 8 + rg) * 16 + fr] = lsum;
  __syncthreads();
  const float lt = lsb[(0 * 8 + rg) * 16 + fr] + lsb[(1 * 8 + rg) * 16 + fr];
  const float ci = -__log2f(lt) - Mq2;   // C-init: log2(1/l) - M*log2e
  __syncthreads();                        // lsb reads done before Vt staging

  // ================= PASS 2: attn write + PV (1 barrier/tile) ================
  f32x4 accv[4];   // ctx^T: col=q(fr), row=dv(g*4+reg)
#pragma unroll
  for (int n = 0; n < 4; ++n) accv[n] = (f32x4){0.f, 0.f, 0.f, 0.f};

  cur = 0;
  if (sk) { LOAD_K(0); STORE_K(0); } else { LOAD_V(0); STORE_V(0); }
  __syncthreads();

  for (int it = 0; it < ntv; ++it) {
    const int k0 = it * 64;
    const bool pre = (it + 1 < ntv);
    const bool lastt = (it == ntv - 1);
    if (pre) {
      if (sk) LOAD_K(k0 + 64);
      else    LOAD_V(k0 + 64);
    }
#pragma unroll
    for (int cc = 0; cc < 2; ++cc) {
      const int c = kh * 2 + cc;
      const int kb = k0 + c * 16 + g * 4;
      const float4 bz = *(const float4*)(biasq + kb);
      const f16x8 ka0 = *(const f16x8*)&Kl[cur][c * 16 + fr][g * 8];
      const f16x8 ka1 = *(const f16x8*)&Kl[cur][c * 16 + fr][32 + g * 8];
      f32x4 acc = {ci, ci, ci, ci};
      acc = __builtin_amdgcn_mfma_f32_16x16x32_f16(ka0, bq[0], acc, 0, 0, 0);
      acc = __builtin_amdgcn_mfma_f32_16x16x32_f16(ka1, bq[1], acc, 0, 0, 0);
      f32x4 pv;
#pragma unroll
      for (int r = 0; r < 4; ++r) pv[r] = fexp2(fmaf(bz[r], LOG2E, acc[r]));
      if (lastt) {
#pragma unroll
        for (int r = 0; r < 4; ++r) pv[r] = (kb + r < vl) ? pv[r] : 0.f;
      }
      *(f32x4*)(attnq + kb) = pv;    // regular store: L2 merges lines
      // P^T fragment = B-operand of 16x16x16f16 (k=g*4+e, n=fr)
      f16x4 ph;
#pragma unroll
      for (int r = 0; r < 4; ++r) ph[r] = (_Float16)pv[r];
#pragma unroll
      for (int n = 0; n < 4; ++n) {
        const f16x4 va = *(const f16x4*)&Vt[cur][n * 16 + fr][c * 16 + g * 4];
        accv[n] = __builtin_amdgcn_mfma_f32_16x16x16f16(va, ph, accv[n], 0, 0, 0);
      }
    }
    if (pre) {
      if (sk) STORE_K(cur ^ 1);
      else    STORE_V(cur ^ 1);
    }
    __syncthreads();             // ONE barrier per tile
    cur ^= 1;
  }

  // ---- pair-reduce accv (overlay red on dead K/V buffers), ctx store ----
  if (kh == 1) {
#pragma unroll
    for (int n = 0; n < 4; ++n)
#pragma unroll
      for (int r = 0; r < 4; ++r)
        red[(rg * 64 + l) * 18 + n * 4 + r] = accv[n][r];
  }
  __syncthreads();
  if (kh == 0) {
#pragma unroll
    for (int n = 0; n < 4; ++n) {
#pragma unroll
      for (int r = 0; r < 4; ++r)
        accv[n][r] += red[(rg * 64 + l) * 18 + n * 4 + r];
      const size_t o = ((size_t)(b * QQ + myq) * HH + h) * DVV + n * 16 + g * 4;
      *(f32x4*)(ctx + o) = accv[n];
    }
  }
#undef KADDR
#undef VADDR
#undef LOAD_K
#undef STORE_K
#undef LOAD_V
#undef STORE_V
}

// ---------------------------------------------------------------------------
extern "C" void kernel_launch(void* const* d_in, const int* in_sizes, int n_in,
                              void* d_out, int out_size, void* d_ws, size_t ws_size,
                              hipStream_t stream) {
  (void)in_sizes; (void)n_in; (void)ws_size; (void)out_size;
  const float* qs   = (const float*)d_in[0];
  const float* ks   = (const float*)d_in[1];
  const float* vs   = (const float*)d_in[2];
  const float* bias = (const float*)d_in[3];
  const int*   vlen = (const int*)d_in[4];
  float* out = (float*)d_out;
  float* ws  = (float*)d_ws;

  prep_norms<<<dim3(256), dim3(256), 0, stream>>>(qs, ks, vlen, ws);
  prep_m<<<dim3(1024), dim3(256), 0, stream>>>(bias, vlen, ws);
  fused_attn<<<dim3(512), dim3(1024), 0, stream>>>(qs, ks, vs, bias, vlen, ws, out);
}

// Round 13
// 266.635 us; speedup vs baseline: 1.1353x; 1.1353x over previous
//
#include <hip/hip_runtime.h>
#include <cstdint>
#include <cstddef>

#define BB 2
#define QQ 2048
#define KK_ 2048
#define HH 16
#define DD 64
#define DVV 64

static constexpr size_t CTX_ELEMS = (size_t)BB * QQ * HH * DVV;  // 4,194,304
#define LOG2E 1.44269504088896f
#define QSCALE (LOG2E / 8.0f)

typedef _Float16 f16x8 __attribute__((ext_vector_type(8)));
typedef _Float16 f16x4 __attribute__((ext_vector_type(4)));
typedef _Float16 f16x2 __attribute__((ext_vector_type(2)));
typedef float    f32x4 __attribute__((ext_vector_type(4)));

__device__ __forceinline__ float fexp2(float x) {
  float r;
  asm("v_exp_f32 %0, %1" : "=v"(r) : "v"(x));
  return r;
}

// workspace layout (float offsets)
#define RQ_OFF    0        // [B][H][Q]  0.125*||q_row||
#define KPART_OFF 65536    // [B*H][8]   partial max ||k_row|| per chunk
#define M_OFF     65792    // [B][H][Q]  upper bound M per row

// ---------------------------------------------------------------------------
// Prep A: per (b,h,chunk): rq rows + partial kmax (over valid k only).
// ---------------------------------------------------------------------------
__global__ __launch_bounds__(256)
void prep_norms(const float* __restrict__ qs, const float* __restrict__ ks,
                const int* __restrict__ vlen, float* __restrict__ ws) {
  float* rq    = ws + RQ_OFF;
  float* kpart = ws + KPART_OFF;
  const int id = blockIdx.x;            // 0..255
  const int bh = id & 31, c = id >> 5;  // chunk 0..7
  const int h = bh & 15, b = bh >> 4;
  const int vl = vlen[b];
  const int t = threadIdx.x;
  const int grp = t >> 4, l16 = t & 15;
  const int w = t >> 6, l = t & 63;
  __shared__ float red[4];
  float km2 = 0.f;                      // max squared norm
  const int base = c * 256;
  for (int i = 0; i < 16; ++i) {
    const int r = base + i * 16 + grp;
    {
      const float4 v = *(const float4*)(qs + ((size_t)(b * QQ + r) * HH + h) * DD + l16 * 4);
      float s = v.x * v.x + v.y * v.y + v.z * v.z + v.w * v.w;
      s += __shfl_xor(s, 1); s += __shfl_xor(s, 2);
      s += __shfl_xor(s, 4); s += __shfl_xor(s, 8);
      if (l16 == 0) rq[(size_t)(b * HH + h) * QQ + r] = sqrtf(s) * 0.125f;
    }
    if (r < vl) {
      const float4 v = *(const float4*)(ks + ((size_t)(b * KK_ + r) * HH + h) * DD + l16 * 4);
      float s = v.x * v.x + v.y * v.y + v.z * v.z + v.w * v.w;
      s += __shfl_xor(s, 1); s += __shfl_xor(s, 2);
      s += __shfl_xor(s, 4); s += __shfl_xor(s, 8);
      km2 = fmaxf(km2, s);
    }
  }
  km2 = fmaxf(km2, __shfl_xor(km2, 16));
  km2 = fmaxf(km2, __shfl_xor(km2, 32));
  if (l == 0) red[w] = km2;
  __syncthreads();
  if (t == 0)
    kpart[bh * 8 + c] = sqrtf(fmaxf(fmaxf(red[0], red[1]), fmaxf(red[2], red[3])));
}

// ---------------------------------------------------------------------------
// Prep B: per (b,q): Brow = max_{k<vl} bias[q,k]; M[b,h,q] = rq*kmax + Brow.
// ---------------------------------------------------------------------------
__global__ __launch_bounds__(256)
void prep_m(const float* __restrict__ bias, const int* __restrict__ vlen,
            float* __restrict__ ws) {
  const float* rq    = ws + RQ_OFF;
  const float* kpart = ws + KPART_OFF;
  float* M = ws + M_OFF;
  const int id = blockIdx.x;            // 0..1023
  const int b = id >> 9;
  const int qb = (id & 511) * 4;
  const int t = threadIdx.x, w = t >> 6, l = t & 63;
  const int q = qb + w;
  const int vl = vlen[b];
  float m = -3e38f;
  for (int k0 = l * 4; k0 < vl; k0 += 256) {
    const float4 v = *(const float4*)(bias + (size_t)q * KK_ + k0);
    m = fmaxf(m, (k0 + 0 < vl) ? v.x : -3e38f);
    m = fmaxf(m, (k0 + 1 < vl) ? v.y : -3e38f);
    m = fmaxf(m, (k0 + 2 < vl) ? v.z : -3e38f);
    m = fmaxf(m, (k0 + 3 < vl) ? v.w : -3e38f);
  }
#pragma unroll
  for (int off = 1; off < 64; off <<= 1) m = fmaxf(m, __shfl_xor(m, off));
  if (l < 16) {
    const int h = l;
    float kmx = 0.f;
#pragma unroll
    for (int cc = 0; cc < 8; ++cc) kmx = fmaxf(kmx, kpart[(b * HH + h) * 8 + cc]);
    M[(size_t)(b * HH + h) * QQ + q] = rq[(size_t)(b * HH + h) * QQ + q] * kmx + m;
  }
}

// ---------------------------------------------------------------------------
// Main fused kernel. wg = (b,h, 128 q-rows), 512 thr (8 waves, 16 q each).
// K-step 128 (paired 64-row buffers, dbuf pairs) -> ONE barrier per 128 k.
// BIAS REGISTER PREFETCH: two float4[4] sets ping-pong at half-tile (64-k)
// granularity, issued one half-tile ahead of use -> L2/L3 latency hidden
// under the previous half-tile's MFMA+exp (the last unprefetched stream).
// exp2 folding: per element just fma + v_exp_f32. Transposed-S MFMA: lane
// (fr,g) holds P^T[k][q] = B-frag of 16x16x16f16 -> PV from registers.
// Mask applied only in the last pair (uniform branch).
// ---------------------------------------------------------------------------
__global__ __launch_bounds__(512, 4)
void fused_attn(const float* __restrict__ qs, const float* __restrict__ ks,
                const float* __restrict__ vs, const float* __restrict__ bias,
                const int* __restrict__ vlen, const float* __restrict__ ws,
                float* __restrict__ dout) {
  float* ctx  = dout;
  float* attn = dout + CTX_ELEMS;
  const float* Mbuf = ws + M_OFF;

  // XCD swizzle: XCD x owns q-tiles {2x,2x+1} x all 32 bh (bias 2MB/XCD in L2)
  const int x   = blockIdx.x;           // 0..511
  const int xcd = x & 7;
  const int j   = x >> 3;               // 0..63
  const int qt  = xcd * 2 + (j & 1);    // 0..15 (128-row tiles)
  const int bh  = j >> 1;               // 0..31
  const int h   = bh & 15, b = bh >> 4;
  const int vl  = vlen[b];
  const int ntv = (vl + 63) >> 6;       // valid 64-tiles
  const int np  = (ntv + 1) >> 1;       // 128-wide pairs (may pad 1 tile)

  const int t = threadIdx.x;
  const int w = t >> 6, l = t & 63, fr = l & 15, g = l >> 4;
  const int q0 = qt * 128, qw = q0 + w * 16;
  const int myq = qw + fr;

  __shared__ _Float16 KS[4][64][72];  // K: two pairs x two 64-row halves
  __shared__ _Float16 VS[4][64][72];  // V^T: same structure

  // ---- zero-fill attn tail beyond processed range ----
  {
    const int row = t >> 2;             // 0..127
    const int c0  = (t & 3) << 4;
    float* ap = attn + ((size_t)(b * HH + h) * QQ + q0 + row) * KK_ + c0;
    const f32x4 z = {0.f, 0.f, 0.f, 0.f};
    for (int k0 = np * 128; k0 < KK_; k0 += 64) {
#pragma unroll
      for (int i = 0; i < 4; ++i) *(f32x4*)(ap + k0 + i * 4) = z;
    }
  }

  // ---- Q B-fragment in registers, pre-scaled by log2e/8 ----
  f16x8 bq[2];
  {
    const float* qp = qs + ((size_t)(b * QQ + myq) * HH + h) * DD + g * 8;
#pragma unroll
    for (int kk = 0; kk < 2; ++kk) {
      const float4 f0 = *(const float4*)(qp + kk * 32);
      const float4 f1 = *(const float4*)(qp + kk * 32 + 4);
      f16x8 v;
      v[0] = (_Float16)(f0.x * QSCALE); v[1] = (_Float16)(f0.y * QSCALE);
      v[2] = (_Float16)(f0.z * QSCALE); v[3] = (_Float16)(f0.w * QSCALE);
      v[4] = (_Float16)(f1.x * QSCALE); v[5] = (_Float16)(f1.y * QSCALE);
      v[6] = (_Float16)(f1.z * QSCALE); v[7] = (_Float16)(f1.w * QSCALE);
      bq[kk] = v;
    }
  }

  const float Mq2 = Mbuf[(size_t)(b * HH + h) * QQ + myq] * LOG2E;
  const float* biasq = bias + (size_t)myq * KK_;
  float* attnq = attn + ((size_t)(b * HH + h) * QQ + myq) * KK_;

  // staging: K 128x64 -> row t>>2, 16 cols (t&3)*16; V pairs per half
  const int krow = t >> 2, kc0 = (t & 3) << 4;
  const int h64 = t >> 8;               // V half 0/1
  const int tt = t & 255;
  const int rho = tt & 31, dlt = tt >> 5;  // dlt 0..7

#define KADDR(k) (ks + ((size_t)(b * KK_ + (k)) * HH + h) * DD)
#define VADDR(k) (vs + ((size_t)(b * KK_ + (k)) * HH + h) * DVV)

#define LOAD_K2(k0arg)                                     \
  do {                                                     \
    const float* kp = KADDR((k0arg) + krow) + kc0;         \
    _Pragma("unroll") for (int i = 0; i < 4; ++i)          \
      kr[i] = ((const float4*)kp)[i];                      \
  } while (0)

#define STORE_K2(pb2)                                      \
  do {                                                     \
    const int khalf = (pb2) + (krow >> 6);                 \
    const int krw = krow & 63;                             \
    _Pragma("unroll") for (int i = 0; i < 4; ++i) {        \
      f16x4 hv;                                            \
      hv[0] = (_Float16)kr[i].x; hv[1] = (_Float16)kr[i].y;\
      hv[2] = (_Float16)kr[i].z; hv[3] = (_Float16)kr[i].w;\
      *(f16x4*)&KS[khalf][krw][kc0 + i * 4] = hv;          \
    }                                                      \
  } while (0)

#define LOAD_V2(k0arg)                                     \
  do {                                                     \
    const float* vp0 = VADDR((k0arg) + h64 * 64 + 2 * rho) + dlt * 8; \
    vr[0] = ((const float4*)vp0)[0];                       \
    vr[1] = ((const float4*)vp0)[1];                       \
    const float* vp1 = VADDR((k0arg) + h64 * 64 + 2 * rho + 1) + dlt * 8; \
    vr[2] = ((const float4*)vp1)[0];                       \
    vr[3] = ((const float4*)vp1)[1];                       \
  } while (0)

#define STORE_V2(pb2)                                      \
  do {                                                     \
    const float a0[8] = {vr[0].x, vr[0].y, vr[0].z, vr[0].w,\
                         vr[1].x, vr[1].y, vr[1].z, vr[1].w};\
    const float a1[8] = {vr[2].x, vr[2].y, vr[2].z, vr[2].w,\
                         vr[3].x, vr[3].y, vr[3].z, vr[3].w};\
    _Pragma("unroll") for (int i = 0; i < 8; ++i) {        \
      f16x2 pk; pk[0] = (_Float16)a0[i]; pk[1] = (_Float16)a1[i];\
      *(f16x2*)&VS[(pb2) + h64][dlt * 8 + i][2 * rho] = pk;\
    }                                                      \
  } while (0)

#define LOAD_BIAS(dst, kbase)                              \
  do {                                                     \
    _Pragma("unroll") for (int c = 0; c < 4; ++c)          \
      dst[c] = *(const float4*)(biasq + (kbase) + c * 16 + g * 4); \
  } while (0)

  float4 kr[4];
  float4 vr[4];
  float4 bzc[4], bzn[4];   // bias ping-pong register sets (half-tile each)

  // ================= PASS 1: lsum (1 barrier per 128 k) ======================
  LOAD_K2(0);
  STORE_K2(0);
  LOAD_BIAS(bzc, 0);
  __syncthreads();

  float lsum = 0.f;
  for (int ip = 0; ip < np; ++ip) {
    const int pb2 = (ip & 1) << 1;
    const bool pre = (ip + 1 < np);
    const bool mpair = (ip == np - 1);
    if (pre) LOAD_K2((ip + 1) * 128);
    // ---- half-tile 0: consume bzc, prefetch bzn (half-tile 1) ----
    LOAD_BIAS(bzn, ip * 128 + 64);
#pragma unroll
    for (int c = 0; c < 4; ++c) {
      const int kb = ip * 128 + c * 16 + g * 4;
      const f16x8 ka0 = *(const f16x8*)&KS[pb2][c * 16 + fr][g * 8];
      const f16x8 ka1 = *(const f16x8*)&KS[pb2][c * 16 + fr][32 + g * 8];
      f32x4 acc = {-Mq2, -Mq2, -Mq2, -Mq2};
      acc = __builtin_amdgcn_mfma_f32_16x16x32_f16(ka0, bq[0], acc, 0, 0, 0);
      acc = __builtin_amdgcn_mfma_f32_16x16x32_f16(ka1, bq[1], acc, 0, 0, 0);
      float e[4];
#pragma unroll
      for (int r = 0; r < 4; ++r) e[r] = fexp2(fmaf(bzc[c][r], LOG2E, acc[r]));
      if (mpair) {
#pragma unroll
        for (int r = 0; r < 4; ++r) e[r] = (kb + r < vl) ? e[r] : 0.f;
      }
      lsum += (e[0] + e[1]) + (e[2] + e[3]);
    }
    // ---- half-tile 1: consume bzn, prefetch bzc (next pair half 0) ----
    LOAD_BIAS(bzc, pre ? (ip + 1) * 128 : 0);
#pragma unroll
    for (int c = 0; c < 4; ++c) {
      const int kb = ip * 128 + 64 + c * 16 + g * 4;
      const f16x8 ka0 = *(const f16x8*)&KS[pb2 + 1][c * 16 + fr][g * 8];
      const f16x8 ka1 = *(const f16x8*)&KS[pb2 + 1][c * 16 + fr][32 + g * 8];
      f32x4 acc = {-Mq2, -Mq2, -Mq2, -Mq2};
      acc = __builtin_amdgcn_mfma_f32_16x16x32_f16(ka0, bq[0], acc, 0, 0, 0);
      acc = __builtin_amdgcn_mfma_f32_16x16x32_f16(ka1, bq[1], acc, 0, 0, 0);
      float e[4];
#pragma unroll
      for (int r = 0; r < 4; ++r) e[r] = fexp2(fmaf(bzn[c][r], LOG2E, acc[r]));
      if (mpair) {
#pragma unroll
        for (int r = 0; r < 4; ++r) e[r] = (kb + r < vl) ? e[r] : 0.f;
      }
      lsum += (e[0] + e[1]) + (e[2] + e[3]);
    }
    if (pre) STORE_K2(pb2 ^ 2);
    __syncthreads();             // ONE barrier per 128 k
  }
  lsum += __shfl_xor(lsum, 16);
  lsum += __shfl_xor(lsum, 32);
  const float ci = -__log2f(lsum) - Mq2;   // pass-2 C-init: log2(il) - M*log2e

  // ================= PASS 2: attn write + PV (1 barrier per 128 k) ===========
  f32x4 accv[4];   // ctx^T: col=q(fr), row=dv(g*4+reg)
#pragma unroll
  for (int n = 0; n < 4; ++n) accv[n] = (f32x4){0.f, 0.f, 0.f, 0.f};

  LOAD_K2(0);
  LOAD_V2(0);
  STORE_K2(0);
  STORE_V2(0);
  LOAD_BIAS(bzc, 0);
  __syncthreads();

  for (int ip = 0; ip < np; ++ip) {
    const int pb2 = (ip & 1) << 1;
    const bool pre = (ip + 1 < np);
    const bool mpair = (ip == np - 1);
    if (pre) {
      LOAD_K2((ip + 1) * 128);
      LOAD_V2((ip + 1) * 128);
    }
    // ---- half-tile 0: consume bzc, prefetch bzn ----
    LOAD_BIAS(bzn, ip * 128 + 64);
#pragma unroll
    for (int c = 0; c < 4; ++c) {
      const int kb = ip * 128 + c * 16 + g * 4;
      const f16x8 ka0 = *(const f16x8*)&KS[pb2][c * 16 + fr][g * 8];
      const f16x8 ka1 = *(const f16x8*)&KS[pb2][c * 16 + fr][32 + g * 8];
      f32x4 acc = {ci, ci, ci, ci};
      acc = __builtin_amdgcn_mfma_f32_16x16x32_f16(ka0, bq[0], acc, 0, 0, 0);
      acc = __builtin_amdgcn_mfma_f32_16x16x32_f16(ka1, bq[1], acc, 0, 0, 0);
      f32x4 pv;
#pragma unroll
      for (int r = 0; r < 4; ++r) pv[r] = fexp2(fmaf(bzc[c][r], LOG2E, acc[r]));
      if (mpair) {
#pragma unroll
        for (int r = 0; r < 4; ++r) pv[r] = (kb + r < vl) ? pv[r] : 0.f;
      }
      *(f32x4*)(attnq + kb) = pv;
      f16x4 ph;
#pragma unroll
      for (int r = 0; r < 4; ++r) ph[r] = (_Float16)pv[r];
#pragma unroll
      for (int n = 0; n < 4; ++n) {
        const f16x4 va = *(const f16x4*)&VS[pb2][n * 16 + fr][c * 16 + g * 4];
        accv[n] = __builtin_amdgcn_mfma_f32_16x16x16f16(va, ph, accv[n], 0, 0, 0);
      }
    }
    // ---- half-tile 1: consume bzn, prefetch bzc ----
    LOAD_BIAS(bzc, pre ? (ip + 1) * 128 : 0);
#pragma unroll
    for (int c = 0; c < 4; ++c) {
      const int kb = ip * 128 + 64 + c * 16 + g * 4;
      const f16x8 ka0 = *(const f16x8*)&KS[pb2 + 1][c * 16 + fr][g * 8];
      const f16x8 ka1 = *(const f16x8*)&KS[pb2 + 1][c * 16 + fr][32 + g * 8];
      f32x4 acc = {ci, ci, ci, ci};
      acc = __builtin_amdgcn_mfma_f32_16x16x32_f16(ka0, bq[0], acc, 0, 0, 0);
      acc = __builtin_amdgcn_mfma_f32_16x16x32_f16(ka1, bq[1], acc, 0, 0, 0);
      f32x4 pv;
#pragma unroll
      for (int r = 0; r < 4; ++r) pv[r] = fexp2(fmaf(bzn[c][r], LOG2E, acc[r]));
      if (mpair) {
#pragma unroll
        for (int r = 0; r < 4; ++r) pv[r] = (kb + r < vl) ? pv[r] : 0.f;
      }
      *(f32x4*)(attnq + kb) = pv;
      f16x4 ph;
#pragma unroll
      for (int r = 0; r < 4; ++r) ph[r] = (_Float16)pv[r];
#pragma unroll
      for (int n = 0; n < 4; ++n) {
        const f16x4 va = *(const f16x4*)&VS[pb2 + 1][n * 16 + fr][c * 16 + g * 4];
        accv[n] = __builtin_amdgcn_mfma_f32_16x16x16f16(va, ph, accv[n], 0, 0, 0);
      }
    }
    if (pre) {
      STORE_K2(pb2 ^ 2);
      STORE_V2(pb2 ^ 2);
    }
    __syncthreads();             // ONE barrier per 128 k
  }

  // ---- ctx store: q = myq, dv = n*16 + g*4 (+r contiguous -> float4) ----
#pragma unroll
  for (int n = 0; n < 4; ++n) {
    const size_t o = ((size_t)(b * QQ + myq) * HH + h) * DVV + n * 16 + g * 4;
    *(f32x4*)(ctx + o) = accv[n];
  }
#undef KADDR
#undef VADDR
#undef LOAD_K2
#undef STORE_K2
#undef LOAD_V2
#undef STORE_V2
#undef LOAD_BIAS
}

// ---------------------------------------------------------------------------
extern "C" void kernel_launch(void* const* d_in, const int* in_sizes, int n_in,
                              void* d_out, int out_size, void* d_ws, size_t ws_size,
                              hipStream_t stream) {
  (void)in_sizes; (void)n_in; (void)ws_size; (void)out_size;
  const float* qs   = (const float*)d_in[0];
  const float* ks   = (const float*)d_in[1];
  const float* vs   = (const float*)d_in[2];
  const float* bias = (const float*)d_in[3];
  const int*   vlen = (const int*)d_in[4];
  float* out = (float*)d_out;
  float* ws  = (float*)d_ws;

  prep_norms<<<dim3(256), dim3(256), 0, stream>>>(qs, ks, vlen, ws);
  prep_m<<<dim3(1024), dim3(256), 0, stream>>>(bias, vlen, ws);
  fused_attn<<<dim3(512), dim3(512), 0, stream>>>(qs, ks, vs, bias, vlen, ws, out);
}